// Round 11
// baseline (160.469 us; speedup 1.0000x reference)
//
#include <hip/hip_runtime.h>
#include <cmath>
#include <stdint.h>

#define DEV __device__ __forceinline__

typedef float v2f __attribute__((ext_vector_type(2)));

static DEV float fast_exp2(float x) { return __builtin_amdgcn_exp2f(x); }
static DEV float fast_rcp(float x) { return __builtin_amdgcn_rcpf(x); }

#define LOG2E 1.4426950408889634f

static DEV float rdl(float x, int l) {
  return __int_as_float(__builtin_amdgcn_readlane(__float_as_int(x), l));
}
static DEV int rdli(float x, int l) {
  return __builtin_amdgcn_readlane(__float_as_int(x), l);
}
// pack two wave-uniform floats into one 64-bit scalar (SGPR pair)
static DEV uint64_t pack2(int lo, int hi) {
  return ((uint64_t)(uint32_t)hi << 32) | (uint32_t)lo;
}

// packed fp32 FMA: acc.{lo,hi} += w.{lo,hi} * h.{lo,hi}; h is an SGPR pair.
static DEV void pkfma(v2f& acc, v2f w, uint64_t h) {
  asm("v_pk_fma_f32 %0, %1, %2, %0" : "+v"(acc) : "v"(w), "s"(h));
}

// broadcast the value held by lane (4j+K) to all lanes of quad j (DPP quad_perm)
template <int K>
static DEV float qb(float x) {
  return __int_as_float(
      __builtin_amdgcn_update_dpp(0, __float_as_int(x), K * 0x55, 0xF, 0xF, true));
}

// m = max(m, dpp_shift(m)); bound_ctrl=true -> invalid lanes read 0.0f,
// safe as identity since all our probabilities are >= 0.
template <int CTRL>
static DEV float dppmax(float x) {
  float o = __int_as_float(
      __builtin_amdgcn_update_dpp(0, __float_as_int(x), CTRL, 0xF, 0xF, true));
  return fmaxf(x, o);
}

// full wave64 max via DPP (VALU only): row_shr 1,2,4,8 then row_bcast15/31.
static DEV float wavemax_bcast(float m) {
  m = dppmax<0x111>(m);
  m = dppmax<0x112>(m);
  m = dppmax<0x114>(m);
  m = dppmax<0x118>(m);
  m = dppmax<0x142>(m);  // row_bcast:15
  m = dppmax<0x143>(m);  // row_bcast:31
  return rdl(m, 63);
}

struct KP {
  const float* tags; const float* lem;
  const float* eWih0; const float* eWhh0; const float* ebih0; const float* ebhh0;
  const float* eWih1; const float* eWhh1; const float* ebih1; const float* ebhh1;
  const float* eWih2; const float* eWhh2; const float* ebih2; const float* ebhh2;
  const float* dWih0; const float* dWhh0; const float* dbih0; const float* dbhh0;
  const float* dWih1; const float* dWhh1; const float* dbih1; const float* dbhh1;
  const float* dWih2; const float* dWhh2; const float* dbih2; const float* dbhh2;
  const float* linW; const float* linb;
  float* outp; float* outt;
  int B;
};

// TWO chains per wave, interleaved in time (software multithreading): weights
// are shared by all chains (one 50-VGPR set); chain B only adds state (h in
// SGPR pairs, c/sp in VGPRs). Interleaved A/B layer bodies fill the serial
// act->DPP->tanh->readlane latency chain of one chain with the other's
// independent instructions — attacking the measured ~15% VALU idle at ~2.4
// resident waves/SIMD. lane = 4*j + k owns gate row (k*10 + j); gate weights
// pre-scaled by the activation constant kc (R10). 8 chains per 256-thr block.
__global__ __launch_bounds__(256) void seq2seq_kernel(KP P) {
  const int tid = threadIdx.x;
  const int lane = tid & 63;
  int bA = blockIdx.x * 8 + (tid >> 6) * 2;
  int bB = bA + 1;
  const bool vA = (bA < P.B), vB = (bB < P.B);
  if (!vA) bA = P.B - 1;
  if (!vB) bB = P.B - 1;

  const int jq = lane >> 2;
  const int kg = lane & 3;
  const int jj = (jq < 10) ? jq : 9;
  const int row = kg * 10 + jj;

  const float kc = (kg == 2) ? (-2.0f * LOG2E) : (-LOG2E);
  const float am = (kg == 2) ? 2.0f : 1.0f;
  const float ab = (kg == 2) ? -1.0f : 0.0f;

  auto act = [&](float g) -> float {
    float y = fast_rcp(1.0f + fast_exp2(g));
    return fmaf(am, y, ab);
  };

  // per-chain uniform data
  float tvA = (lane < 63) ? P.tags[(size_t)bA * 63 + lane] : 0.0f;
  float tvB = (lane < 63) ? P.tags[(size_t)bB * 63 + lane] : 0.0f;
  float lemA = (lane < 32) ? P.lem[(size_t)bA * 32 + lane] : 0.0f;
  float lemB = (lane < 32) ? P.lem[(size_t)bB * 32 + lane] : 0.0f;

  // --- fold the tag contribution into the layer-0 pre-biases (both chains) ---
  float ebias = P.ebih0[row] + P.ebhh0[row];
  float dbias = P.dbih0[row] + P.dbhh0[row];
  float pre0A = ebias, pre0B = ebias, dpre0A = dbias, dpre0B = dbias;
  float ew0c, dw0c;
  {
    const float4* e4 = (const float4*)P.eWih0 + row * 16;
    const float4* d4 = (const float4*)P.dWih0 + row * 16;
    float4 we = e4[0], wd = d4[0];
    ew0c = we.x; dw0c = wd.x;
    {
      float a0 = rdl(tvA, 0), a1 = rdl(tvA, 1), a2 = rdl(tvA, 2);
      float b0 = rdl(tvB, 0), b1 = rdl(tvB, 1), b2 = rdl(tvB, 2);
      pre0A = fmaf(we.y, a0, pre0A); pre0A = fmaf(we.z, a1, pre0A); pre0A = fmaf(we.w, a2, pre0A);
      pre0B = fmaf(we.y, b0, pre0B); pre0B = fmaf(we.z, b1, pre0B); pre0B = fmaf(we.w, b2, pre0B);
      dpre0A = fmaf(wd.y, a0, dpre0A); dpre0A = fmaf(wd.z, a1, dpre0A); dpre0A = fmaf(wd.w, a2, dpre0A);
      dpre0B = fmaf(wd.y, b0, dpre0B); dpre0B = fmaf(wd.z, b1, dpre0B); dpre0B = fmaf(wd.w, b2, dpre0B);
    }
#pragma unroll
    for (int c = 1; c < 16; c++) {
      float4 e = e4[c], d = d4[c];
      int dd = 4 * c - 1;
      float a0 = rdl(tvA, dd), a1 = rdl(tvA, dd + 1), a2 = rdl(tvA, dd + 2), a3 = rdl(tvA, dd + 3);
      float b0 = rdl(tvB, dd), b1 = rdl(tvB, dd + 1), b2 = rdl(tvB, dd + 2), b3 = rdl(tvB, dd + 3);
      pre0A = fmaf(e.x, a0, pre0A); pre0A = fmaf(e.y, a1, pre0A);
      pre0A = fmaf(e.z, a2, pre0A); pre0A = fmaf(e.w, a3, pre0A);
      pre0B = fmaf(e.x, b0, pre0B); pre0B = fmaf(e.y, b1, pre0B);
      pre0B = fmaf(e.z, b2, pre0B); pre0B = fmaf(e.w, b3, pre0B);
      dpre0A = fmaf(d.x, a0, dpre0A); dpre0A = fmaf(d.y, a1, dpre0A);
      dpre0A = fmaf(d.z, a2, dpre0A); dpre0A = fmaf(d.w, a3, dpre0A);
      dpre0B = fmaf(d.x, b0, dpre0B); dpre0B = fmaf(d.y, b1, dpre0B);
      dpre0B = fmaf(d.z, b2, dpre0B); dpre0B = fmaf(d.w, b3, dpre0B);
    }
    pre0A *= kc; pre0B *= kc; dpre0A *= kc; dpre0B *= kc;
    ew0c *= kc; dw0c *= kc;
  }

  // --- encoder weights as VGPR pairs, pre-scaled by kc (SHARED by chains) ---
  v2f ehh0[5], eih1[5], ehh1[5], eih2[5], ehh2[5];
  {
    const v2f* a0 = (const v2f*)(P.eWhh0 + row * 10);
    const v2f* a1 = (const v2f*)(P.eWih1 + row * 10);
    const v2f* a2 = (const v2f*)(P.eWhh1 + row * 10);
    const v2f* a3 = (const v2f*)(P.eWih2 + row * 10);
    const v2f* a4 = (const v2f*)(P.eWhh2 + row * 10);
#pragma unroll
    for (int q = 0; q < 5; q++) {
      ehh0[q] = a0[q] * kc; eih1[q] = a1[q] * kc; ehh1[q] = a2[q] * kc;
      eih2[q] = a3[q] * kc; ehh2[q] = a4[q] * kc;
    }
  }
  float pre1 = (P.ebih1[row] + P.ebhh1[row]) * kc;
  float pre2 = (P.ebih2[row] + P.ebhh2[row]) * kc;

  // state: h as SGPR pairs; c per-quad in VGPRs — one set per chain
  uint64_t h0A[5], h1A[5], h2A[5], h0B[5], h1B[5], h2B[5];
#pragma unroll
  for (int q = 0; q < 5; q++) {
    h0A[q] = 0; h1A[q] = 0; h2A[q] = 0;
    h0B[q] = 0; h1B[q] = 0; h2B[q] = 0;
  }
  float cA0 = 0.0f, cA1 = 0.0f, cA2 = 0.0f;
  float cB0 = 0.0f, cB1 = 0.0f, cB2 = 0.0f;

  auto upd = [&](float a, float& c, uint64_t (&h)[5]) {
    float a0 = qb<0>(a);  // sigmoid(i)
    float a1 = qb<1>(a);  // sigmoid(f)
    float a2 = qb<2>(a);  // tanh(g~)
    float a3 = qb<3>(a);  // sigmoid(o)
    c = fmaf(a1, c, a0 * a2);
    float y = fast_rcp(1.0f + fast_exp2(c * (-2.0f * LOG2E)));
    float hv = a3 * fmaf(2.0f, y, -1.0f);
#pragma unroll
    for (int q = 0; q < 5; q++) h[q] = pack2(rdli(hv, 8 * q), rdli(hv, 8 * q + 4));
  };

  auto tdot = [&](const v2f (&w)[5], const uint64_t (&h)[5]) -> float {
    v2f ta{0.0f, 0.0f}, tb{0.0f, 0.0f};
    pkfma(ta, w[0], h[0]); pkfma(tb, w[1], h[1]);
    pkfma(ta, w[2], h[2]); pkfma(tb, w[3], h[3]);
    pkfma(ta, w[4], h[4]);
    return (ta.x + ta.y) + (tb.x + tb.y);
  };

  // interleaved 2-chain step: self-recurrent partials for both chains first,
  // then layer bodies alternating A/B so each fills the other's latency.
  auto stepAB = [&](float xA, float xB) {
    v2f s0A{pre0A, 0.0f}, s1A{pre1, 0.0f}, s2A{pre2, 0.0f};
    v2f s0B{pre0B, 0.0f}, s1B{pre1, 0.0f}, s2B{pre2, 0.0f};
#pragma unroll
    for (int q = 0; q < 5; q++) {
      pkfma(s0A, ehh0[q], h0A[q]); pkfma(s0B, ehh0[q], h0B[q]);
      pkfma(s1A, ehh1[q], h1A[q]); pkfma(s1B, ehh1[q], h1B[q]);
      pkfma(s2A, ehh2[q], h2A[q]); pkfma(s2B, ehh2[q], h2B[q]);
    }
    upd(act(fmaf(ew0c, xA, s0A.x + s0A.y)), cA0, h0A);
    upd(act(fmaf(ew0c, xB, s0B.x + s0B.y)), cB0, h0B);
    upd(act((s1A.x + s1A.y) + tdot(eih1, h0A)), cA1, h1A);
    upd(act((s1B.x + s1B.y) + tdot(eih1, h0B)), cB1, h1B);
    upd(act((s2A.x + s2A.y) + tdot(eih2, h1A)), cA2, h2A);
    upd(act((s2B.x + s2B.y) + tdot(eih2, h1B)), cB2, h2B);
  };

  // ---------------- encoder: 32 steps ----------------
  for (int t = 0; t < 32; t++) stepAB(rdl(lemA, t), rdl(lemB, t));

  // --- decoder weights overwrite the same registers (pre-scaled by kc) ---
  {
    const v2f* a0 = (const v2f*)(P.dWhh0 + row * 10);
    const v2f* a1 = (const v2f*)(P.dWih1 + row * 10);
    const v2f* a2 = (const v2f*)(P.dWhh1 + row * 10);
    const v2f* a3 = (const v2f*)(P.dWih2 + row * 10);
    const v2f* a4 = (const v2f*)(P.dWhh2 + row * 10);
#pragma unroll
    for (int q = 0; q < 5; q++) {
      ehh0[q] = a0[q] * kc; eih1[q] = a1[q] * kc; ehh1[q] = a2[q] * kc;
      eih2[q] = a3[q] * kc; ehh2[q] = a4[q] * kc;
    }
  }
  pre1 = (P.dbih1[row] + P.dbhh1[row]) * kc;
  pre2 = (P.dbih2[row] + P.dbhh2[row]) * kc;

  // linear layer: rows lane and (64+lane if lane<36), pre-scaled by -log2e
  const int lr2 = (lane < 36) ? (64 + lane) : 99;
  v2f lw0[5], lw1[5];
  {
    const v2f* a0 = (const v2f*)(P.linW + lane * 10);
    const v2f* a1 = (const v2f*)(P.linW + lr2 * 10);
#pragma unroll
    for (int q = 0; q < 5; q++) { lw0[q] = a0[q] * (-LOG2E); lw1[q] = a1[q] * (-LOG2E); }
  }
  float lb0 = P.linb[lane] * (-LOG2E);
  float lb1 = ((lane < 36) ? P.linb[lr2] : -1e30f) * (-LOG2E);

  float* opA = P.outp + (size_t)bA * 3000;
  float* opB = P.outp + (size_t)bB * 3000;
  float tokA = 1.0f, tokB = 1.0f;   // START
  float tokvA = 0.0f, tokvB = 0.0f;

  // initial self-recurrent partials from encoder-final state (both chains)
  v2f sp0A{dpre0A, 0.0f}, sp1A{pre1, 0.0f}, sp2A{pre2, 0.0f};
  v2f sp0B{dpre0B, 0.0f}, sp1B{pre1, 0.0f}, sp2B{pre2, 0.0f};
#pragma unroll
  for (int q = 0; q < 5; q++) {
    pkfma(sp0A, ehh0[q], h0A[q]); pkfma(sp0B, ehh0[q], h0B[q]);
    pkfma(sp1A, ehh1[q], h1A[q]); pkfma(sp1B, ehh1[q], h1B[q]);
    pkfma(sp2A, ehh2[q], h2A[q]); pkfma(sp2B, ehh2[q], h2B[q]);
  }

  // ---------------- decoder: 30 steps ----------------
  for (int s = 0; s < 30; s++) {
    upd(act(fmaf(dw0c, tokA, sp0A.x + sp0A.y)), cA0, h0A);
    upd(act(fmaf(dw0c, tokB, sp0B.x + sp0B.y)), cB0, h0B);
    upd(act((sp1A.x + sp1A.y) + tdot(eih1, h0A)), cA1, h1A);
    upd(act((sp1B.x + sp1B.y) + tdot(eih1, h0B)), cB1, h1B);
    upd(act((sp2A.x + sp2A.y) + tdot(eih2, h1A)), cA2, h2A);
    upd(act((sp2B.x + sp2B.y) + tdot(eih2, h1B)), cB2, h2B);

    // next-step self-recurrent partials (overlap the linear/argmax tail)
    sp0A = v2f{dpre0A, 0.0f}; sp1A = v2f{pre1, 0.0f}; sp2A = v2f{pre2, 0.0f};
    sp0B = v2f{dpre0B, 0.0f}; sp1B = v2f{pre1, 0.0f}; sp2B = v2f{pre2, 0.0f};
#pragma unroll
    for (int q = 0; q < 5; q++) {
      pkfma(sp0A, ehh0[q], h0A[q]); pkfma(sp0B, ehh0[q], h0B[q]);
      pkfma(sp1A, ehh1[q], h1A[q]); pkfma(sp1B, ehh1[q], h1B[q]);
      pkfma(sp2A, ehh2[q], h2A[q]); pkfma(sp2B, ehh2[q], h2B[q]);
    }

    // linear + sigmoid, both chains (weights pre-scaled: p = rcp(1+exp2(z)))
    v2f zaA{lb0, 0.0f}, zbA{lb1, 0.0f}, zaB{lb0, 0.0f}, zbB{lb1, 0.0f};
#pragma unroll
    for (int q = 0; q < 5; q++) {
      pkfma(zaA, lw0[q], h2A[q]); pkfma(zbA, lw1[q], h2A[q]);
      pkfma(zaB, lw0[q], h2B[q]); pkfma(zbB, lw1[q], h2B[q]);
    }
    float p0A = fast_rcp(1.0f + fast_exp2(zaA.x + zaA.y));
    float p1A = fast_rcp(1.0f + fast_exp2(zbA.x + zbA.y));  // lanes>=36: 0
    float p0B = fast_rcp(1.0f + fast_exp2(zaB.x + zaB.y));
    float p1B = fast_rcp(1.0f + fast_exp2(zbB.x + zbB.y));

    if (vA) {
      float* op = opA + s * 100;
      op[lane] = p0A;
      if (lane < 36) op[64 + lane] = p1A;
    }
    if (vB) {
      float* op = opB + s * 100;
      op[lane] = p0B;
      if (lane < 36) op[64 + lane] = p1B;
    }

    // argmax, first-occurrence (both chains; DPP chains interleave)
    float vmA = wavemax_bcast(fmaxf(p0A, p1A));
    float vmB = wavemax_bcast(fmaxf(p0B, p1B));
    unsigned long long m0A = __ballot(p0A == vmA);
    unsigned long long m1A = __ballot(p1A == vmA);
    unsigned long long m0B = __ballot(p0B == vmB);
    unsigned long long m1B = __ballot(p1B == vmB);
    int imA = m0A ? (int)__builtin_ctzll(m0A) : 64 + (int)__builtin_ctzll(m1A);
    int imB = m0B ? (int)__builtin_ctzll(m0B) : 64 + (int)__builtin_ctzll(m1B);
    tokA = (float)imA;
    tokB = (float)imB;
    tokvA = (lane == s) ? tokA : tokvA;
    tokvB = (lane == s) ? tokB : tokvB;
  }

  if (lane < 30 && vA) P.outt[(size_t)bA * 30 + lane] = tokvA;
  if (lane < 30 && vB) P.outt[(size_t)bB * 30 + lane] = tokvB;
}

extern "C" void kernel_launch(void* const* d_in, const int* in_sizes, int n_in,
                              void* d_out, int out_size, void* d_ws, size_t ws_size,
                              hipStream_t stream) {
  KP P;
  P.tags = (const float*)d_in[2];
  P.lem = (const float*)d_in[3];
  P.eWih0 = (const float*)d_in[4];  P.eWhh0 = (const float*)d_in[5];
  P.ebih0 = (const float*)d_in[6];  P.ebhh0 = (const float*)d_in[7];
  P.eWih1 = (const float*)d_in[8];  P.eWhh1 = (const float*)d_in[9];
  P.ebih1 = (const float*)d_in[10]; P.ebhh1 = (const float*)d_in[11];
  P.eWih2 = (const float*)d_in[12]; P.eWhh2 = (const float*)d_in[13];
  P.ebih2 = (const float*)d_in[14]; P.ebhh2 = (const float*)d_in[15];
  P.dWih0 = (const float*)d_in[16]; P.dWhh0 = (const float*)d_in[17];
  P.dbih0 = (const float*)d_in[18]; P.dbhh0 = (const float*)d_in[19];
  P.dWih1 = (const float*)d_in[20]; P.dWhh1 = (const float*)d_in[21];
  P.dbih1 = (const float*)d_in[22]; P.dbhh1 = (const float*)d_in[23];
  P.dWih2 = (const float*)d_in[24]; P.dWhh2 = (const float*)d_in[25];
  P.dbih2 = (const float*)d_in[26]; P.dbhh2 = (const float*)d_in[27];
  P.linW = (const float*)d_in[28];
  P.linb = (const float*)d_in[29];

  const int B = in_sizes[3] / 32;  // lemmata is (B, 32)
  P.B = B;
  P.outp = (float*)d_out;
  P.outt = P.outp + (size_t)B * 3000;

  const int blocks = (B + 7) / 8;  // 8 chains (4 waves x 2) per 256-thr block
  seq2seq_kernel<<<dim3(blocks), dim3(256), 0, stream>>>(P);
}

// Round 12
// 152.487 us; speedup vs baseline: 1.0523x; 1.0523x over previous
//
#include <hip/hip_runtime.h>
#include <cmath>
#include <stdint.h>

#define DEV __device__ __forceinline__

typedef float v2f __attribute__((ext_vector_type(2)));

static DEV float fast_exp2(float x) { return __builtin_amdgcn_exp2f(x); }
static DEV float fast_rcp(float x) { return __builtin_amdgcn_rcpf(x); }

#define LOG2E 1.4426950408889634f

static DEV float rdl(float x, int l) {
  return __int_as_float(__builtin_amdgcn_readlane(__float_as_int(x), l));
}
static DEV int rdli(float x, int l) {
  return __builtin_amdgcn_readlane(__float_as_int(x), l);
}
// pack two wave-uniform floats into one 64-bit scalar (SGPR pair)
static DEV uint64_t pack2(int lo, int hi) {
  return ((uint64_t)(uint32_t)hi << 32) | (uint32_t)lo;
}

// packed fp32 FMA: acc.{lo,hi} += w.{lo,hi} * h.{lo,hi}; h is an SGPR pair.
static DEV void pkfma(v2f& acc, v2f w, uint64_t h) {
  asm("v_pk_fma_f32 %0, %1, %2, %0" : "+v"(acc) : "v"(w), "s"(h));
}

// broadcast the value held by lane (4j+K) to all lanes of quad j (DPP quad_perm)
template <int K>
static DEV float qb(float x) {
  return __int_as_float(
      __builtin_amdgcn_update_dpp(0, __float_as_int(x), K * 0x55, 0xF, 0xF, true));
}

// m = max(m, dpp_shift(m)); bound_ctrl=true -> invalid lanes read 0.0f,
// safe as identity since all our probabilities are >= 0.
template <int CTRL>
static DEV float dppmax(float x) {
  float o = __int_as_float(
      __builtin_amdgcn_update_dpp(0, __float_as_int(x), CTRL, 0xF, 0xF, true));
  return fmaxf(x, o);
}

// full wave64 max via DPP (VALU only): row_shr 1,2,4,8 then row_bcast15/31.
static DEV float wavemax_bcast(float m) {
  m = dppmax<0x111>(m);
  m = dppmax<0x112>(m);
  m = dppmax<0x114>(m);
  m = dppmax<0x118>(m);
  m = dppmax<0x142>(m);  // row_bcast:15
  m = dppmax<0x143>(m);  // row_bcast:31
  return rdl(m, 63);
}

struct KP {
  const float* tags; const float* lem;
  const float* eWih0; const float* eWhh0; const float* ebih0; const float* ebhh0;
  const float* eWih1; const float* eWhh1; const float* ebih1; const float* ebhh1;
  const float* eWih2; const float* eWhh2; const float* ebih2; const float* ebhh2;
  const float* dWih0; const float* dWhh0; const float* dbih0; const float* dbhh0;
  const float* dWih1; const float* dWhh1; const float* dbih1; const float* dbhh1;
  const float* dWih2; const float* dWhh2; const float* dbih2; const float* dbhh2;
  const float* linW; const float* linb;
  float* outp; float* outt;
  int B;
};

// One wave (64 lanes) per batch chain; ONE WAVE PER WORKGROUP (64-thr blocks,
// 8192 blocks) — probing the residency cap seen at 256-thr blocks
// (OccupancyPercent ~29% despite VGPR=84 allowing ~6 waves/SIMD).
// lane = 4*j + k : lane owns gate row (k*10 + j); k: 0=i, 1=f, 2=g~, 3=o.
// Lanes 40..63 (j>=10) are clamped to j=9 and compute harmless duplicates.
// Dots use v_pk_fma_f32: weights in VGPR pairs, h replicated as SGPR pairs.
// Gate weights/biases pre-scaled by the activation constant kc; linear
// weights/bias pre-scaled by -log2e. Decoder computes next-step
// self-recurrent partials before the linear/argmax tail (overlap).
__global__ __launch_bounds__(64) void seq2seq_kernel(KP P) {
  const int lane = threadIdx.x & 63;
  const int b = blockIdx.x;
  if (b >= P.B) return;

  const int jq = lane >> 2;
  const int kg = lane & 3;
  const int jj = (jq < 10) ? jq : 9;
  const int row = kg * 10 + jj;

  const float kc = (kg == 2) ? (-2.0f * LOG2E) : (-LOG2E);
  const float am = (kg == 2) ? 2.0f : 1.0f;
  const float ab = (kg == 2) ? -1.0f : 0.0f;

  auto act = [&](float g) -> float {
    float y = fast_rcp(1.0f + fast_exp2(g));
    return fmaf(am, y, ab);
  };

  // per-chain uniform data
  float tv = (lane < 63) ? P.tags[(size_t)b * 63 + lane] : 0.0f;
  float lemv = (lane < 32) ? P.lem[(size_t)b * 32 + lane] : 0.0f;

  // --- fold the (time-constant) tag contribution into the layer-0 biases ---
  float pre0 = P.ebih0[row] + P.ebhh0[row];
  float dpre0 = P.dbih0[row] + P.dbhh0[row];
  float ew0c, dw0c;
  {
    const float4* e4 = (const float4*)P.eWih0 + row * 16;
    const float4* d4 = (const float4*)P.dWih0 + row * 16;
    float4 we = e4[0], wd = d4[0];
    ew0c = we.x; dw0c = wd.x;
    float t0 = rdl(tv, 0), t1 = rdl(tv, 1), t2 = rdl(tv, 2);
    pre0 = fmaf(we.y, t0, pre0); pre0 = fmaf(we.z, t1, pre0); pre0 = fmaf(we.w, t2, pre0);
    dpre0 = fmaf(wd.y, t0, dpre0); dpre0 = fmaf(wd.z, t1, dpre0); dpre0 = fmaf(wd.w, t2, dpre0);
#pragma unroll
    for (int c = 1; c < 16; c++) {
      float4 e = e4[c], d = d4[c];
      int dd = 4 * c - 1;
      float u0 = rdl(tv, dd), u1 = rdl(tv, dd + 1), u2 = rdl(tv, dd + 2), u3 = rdl(tv, dd + 3);
      pre0 = fmaf(e.x, u0, pre0); pre0 = fmaf(e.y, u1, pre0);
      pre0 = fmaf(e.z, u2, pre0); pre0 = fmaf(e.w, u3, pre0);
      dpre0 = fmaf(d.x, u0, dpre0); dpre0 = fmaf(d.y, u1, dpre0);
      dpre0 = fmaf(d.z, u2, dpre0); dpre0 = fmaf(d.w, u3, dpre0);
    }
    pre0 *= kc; dpre0 *= kc; ew0c *= kc; dw0c *= kc;
  }

  // --- encoder weights as VGPR pairs, pre-scaled by kc ---
  v2f ehh0[5], eih1[5], ehh1[5], eih2[5], ehh2[5];
  {
    const v2f* a0 = (const v2f*)(P.eWhh0 + row * 10);
    const v2f* a1 = (const v2f*)(P.eWih1 + row * 10);
    const v2f* a2 = (const v2f*)(P.eWhh1 + row * 10);
    const v2f* a3 = (const v2f*)(P.eWih2 + row * 10);
    const v2f* a4 = (const v2f*)(P.eWhh2 + row * 10);
#pragma unroll
    for (int q = 0; q < 5; q++) {
      ehh0[q] = a0[q] * kc; eih1[q] = a1[q] * kc; ehh1[q] = a2[q] * kc;
      eih2[q] = a3[q] * kc; ehh2[q] = a4[q] * kc;
    }
  }
  float pre1 = (P.ebih1[row] + P.ebhh1[row]) * kc;
  float pre2 = (P.ebih2[row] + P.ebhh2[row]) * kc;

  // state: h replicated as SGPR pairs {h_{2q}, h_{2q+1}}; c lives per-quad
  uint64_t h0[5], h1[5], h2[5];
#pragma unroll
  for (int q = 0; q < 5; q++) { h0[q] = 0; h1[q] = 0; h2[q] = 0; }
  float c0 = 0.0f, c1 = 0.0f, c2 = 0.0f;

  auto upd = [&](float a, float& c, uint64_t (&h)[5]) {
    float a0 = qb<0>(a);  // sigmoid(i)
    float a1 = qb<1>(a);  // sigmoid(f)
    float a2 = qb<2>(a);  // tanh(g~)
    float a3 = qb<3>(a);  // sigmoid(o)
    c = fmaf(a1, c, a0 * a2);
    // tanh(c) = 2*sigmoid(2c)-1; exp2 over/underflow saturates correctly
    float y = fast_rcp(1.0f + fast_exp2(c * (-2.0f * LOG2E)));
    float hv = a3 * fmaf(2.0f, y, -1.0f);
#pragma unroll
    for (int q = 0; q < 5; q++) h[q] = pack2(rdli(hv, 8 * q), rdli(hv, 8 * q + 4));
  };

  // 2-accumulator t-dot (3-deep chain instead of 5)
  auto tdot = [&](const v2f (&w)[5], const uint64_t (&h)[5]) -> float {
    v2f ta{0.0f, 0.0f}, tb{0.0f, 0.0f};
    pkfma(ta, w[0], h[0]); pkfma(tb, w[1], h[1]);
    pkfma(ta, w[2], h[2]); pkfma(tb, w[3], h[3]);
    pkfma(ta, w[4], h[4]);
    return (ta.x + ta.y) + (tb.x + tb.y);
  };

  // encoder step: self-recurrent partials first, x folded late
  auto step = [&](float x) {
    v2f s0{pre0, 0.0f}, s1{pre1, 0.0f}, s2{pre2, 0.0f};
#pragma unroll
    for (int q = 0; q < 5; q++) {
      pkfma(s0, ehh0[q], h0[q]);
      pkfma(s1, ehh1[q], h1[q]);
      pkfma(s2, ehh2[q], h2[q]);
    }
    upd(act(fmaf(ew0c, x, s0.x + s0.y)), c0, h0);
    upd(act((s1.x + s1.y) + tdot(eih1, h0)), c1, h1);
    upd(act((s2.x + s2.y) + tdot(eih2, h1)), c2, h2);
  };

  // ---------------- encoder: 32 steps ----------------
#pragma unroll 2
  for (int t = 0; t < 32; t++) step(rdl(lemv, t));

  // --- decoder weights overwrite the same registers (pre-scaled by kc) ---
  {
    const v2f* a0 = (const v2f*)(P.dWhh0 + row * 10);
    const v2f* a1 = (const v2f*)(P.dWih1 + row * 10);
    const v2f* a2 = (const v2f*)(P.dWhh1 + row * 10);
    const v2f* a3 = (const v2f*)(P.dWih2 + row * 10);
    const v2f* a4 = (const v2f*)(P.dWhh2 + row * 10);
#pragma unroll
    for (int q = 0; q < 5; q++) {
      ehh0[q] = a0[q] * kc; eih1[q] = a1[q] * kc; ehh1[q] = a2[q] * kc;
      eih2[q] = a3[q] * kc; ehh2[q] = a4[q] * kc;
    }
  }
  pre1 = (P.dbih1[row] + P.dbhh1[row]) * kc;
  pre2 = (P.dbih2[row] + P.dbhh2[row]) * kc;

  // linear layer: rows lane and (64+lane if lane<36), pre-scaled by -log2e
  const int lr2 = (lane < 36) ? (64 + lane) : 99;
  v2f lw0[5], lw1[5];
  {
    const v2f* a0 = (const v2f*)(P.linW + lane * 10);
    const v2f* a1 = (const v2f*)(P.linW + lr2 * 10);
#pragma unroll
    for (int q = 0; q < 5; q++) { lw0[q] = a0[q] * (-LOG2E); lw1[q] = a1[q] * (-LOG2E); }
  }
  float lb0 = P.linb[lane] * (-LOG2E);
  // invalid lanes: -1e30 scales to +1.4e30 -> exp2 -> inf -> rcp -> p1 = 0
  float lb1 = ((lane < 36) ? P.linb[lr2] : -1e30f) * (-LOG2E);

  float* op0 = P.outp + (size_t)b * 3000;
  float tok = 1.0f;   // START
  float tokv = 0.0f;  // lane s accumulates step-s token

  // initial self-recurrent partials from encoder-final state
  v2f sp0{dpre0, 0.0f}, sp1{pre1, 0.0f}, sp2{pre2, 0.0f};
#pragma unroll
  for (int q = 0; q < 5; q++) {
    pkfma(sp0, ehh0[q], h0[q]);
    pkfma(sp1, ehh1[q], h1[q]);
    pkfma(sp2, ehh2[q], h2[q]);
  }

  // ---------------- decoder: 30 steps ----------------
#pragma unroll 2
  for (int s = 0; s < 30; s++) {
    // LSTM layers (tok enters via one fma; partials were precomputed)
    upd(act(fmaf(dw0c, tok, sp0.x + sp0.y)), c0, h0);
    upd(act((sp1.x + sp1.y) + tdot(eih1, h0)), c1, h1);
    upd(act((sp2.x + sp2.y) + tdot(eih2, h1)), c2, h2);

    // next-step self-recurrent partials NOW — independent of linear/argmax,
    // overlaps the serial tail below
    sp0 = v2f{dpre0, 0.0f}; sp1 = v2f{pre1, 0.0f}; sp2 = v2f{pre2, 0.0f};
#pragma unroll
    for (int q = 0; q < 5; q++) {
      pkfma(sp0, ehh0[q], h0[q]);
      pkfma(sp1, ehh1[q], h1[q]);
      pkfma(sp2, ehh2[q], h2[q]);
    }

    // linear + sigmoid (weights pre-scaled: p = rcp(1+exp2(z)))
    v2f za{lb0, 0.0f}, zb{lb1, 0.0f};
#pragma unroll
    for (int q = 0; q < 5; q++) { pkfma(za, lw0[q], h2[q]); pkfma(zb, lw1[q], h2[q]); }
    float p0 = fast_rcp(1.0f + fast_exp2(za.x + za.y));
    float p1 = fast_rcp(1.0f + fast_exp2(zb.x + zb.y));  // lanes>=36: exactly 0

    float* op = op0 + s * 100;
    op[lane] = p0;
    if (lane < 36) op[64 + lane] = p1;

    // argmax, first-occurrence: DPP wave-max (VALU) + ballot/ctz (SALU).
    // fmax returns one of its inputs bitwise, so vm matches some p exactly.
    float vm = wavemax_bcast(fmaxf(p0, p1));
    unsigned long long m0 = __ballot(p0 == vm);
    unsigned long long m1 = __ballot(p1 == vm);
    int im = m0 ? (int)__builtin_ctzll(m0) : 64 + (int)__builtin_ctzll(m1);
    tok = (float)im;
    tokv = (lane == s) ? tok : tokv;
  }

  if (lane < 30) P.outt[(size_t)b * 30 + lane] = tokv;
}

extern "C" void kernel_launch(void* const* d_in, const int* in_sizes, int n_in,
                              void* d_out, int out_size, void* d_ws, size_t ws_size,
                              hipStream_t stream) {
  KP P;
  P.tags = (const float*)d_in[2];
  P.lem = (const float*)d_in[3];
  P.eWih0 = (const float*)d_in[4];  P.eWhh0 = (const float*)d_in[5];
  P.ebih0 = (const float*)d_in[6];  P.ebhh0 = (const float*)d_in[7];
  P.eWih1 = (const float*)d_in[8];  P.eWhh1 = (const float*)d_in[9];
  P.ebih1 = (const float*)d_in[10]; P.ebhh1 = (const float*)d_in[11];
  P.eWih2 = (const float*)d_in[12]; P.eWhh2 = (const float*)d_in[13];
  P.ebih2 = (const float*)d_in[14]; P.ebhh2 = (const float*)d_in[15];
  P.dWih0 = (const float*)d_in[16]; P.dWhh0 = (const float*)d_in[17];
  P.dbih0 = (const float*)d_in[18]; P.dbhh0 = (const float*)d_in[19];
  P.dWih1 = (const float*)d_in[20]; P.dWhh1 = (const float*)d_in[21];
  P.dbih1 = (const float*)d_in[22]; P.dbhh1 = (const float*)d_in[23];
  P.dWih2 = (const float*)d_in[24]; P.dWhh2 = (const float*)d_in[25];
  P.dbih2 = (const float*)d_in[26]; P.dbhh2 = (const float*)d_in[27];
  P.linW = (const float*)d_in[28];
  P.linb = (const float*)d_in[29];

  const int B = in_sizes[3] / 32;  // lemmata is (B, 32)
  P.B = B;
  P.outp = (float*)d_out;
  P.outt = P.outp + (size_t)B * 3000;

  // one wave per workgroup: finer dispatch granularity -> higher co-residency
  seq2seq_kernel<<<dim3(B), dim3(64), 0, stream>>>(P);
}